// Round 5
// baseline (240.731 us; speedup 1.0000x reference)
//
#include <hip/hip_runtime.h>
#include <stdint.h>

// out[b,s,d] = x[b,s,d] + pe[s,d]   (fp32 in/out — proven by WRITE_SIZE=134MB, R3)
//   pe[s,d] = (d even) ? sin(s * 10000^(-2d/1024)) : cos(s * 10000^(-2d/1024))
// Shape (8, 4096, 1024). Traffic: 134 MB read + 134 MB write -> ~43 us @ 6.3 TB/s.
//
// R4 post-mortem: float4+batch-amortized kernel stayed ~85 us. Suspects:
// nontemporal hints degrading the cache path (plain-store fills hit 6.6 TB/s;
// L3 serves ~half the input reads from the harness restore copy) and libm
// sinf/cosf slow-path reduction. This round: plain loads/stores + HW trig
// (v_sin_f32/v_cos_f32 take REVOLUTIONS; explicit v_fract range reduction).
// Added trig error <= ~4e-4 vs threshold 0.124.

constexpr int MODEL_DIM = 1024;
constexpr int SEQ = 4096;
constexpr int BATCH = 8;
constexpr int SD = SEQ * MODEL_DIM;               // 4,194,304
constexpr float C_FREQ = -0.025952563241307517f;  // -log2(10000)/512
constexpr float INV_2PI = 0.15915494309189535f;   // 1/(2*pi)

typedef float v4f __attribute__((ext_vector_type(4)));

__global__ __launch_bounds__(256) void pe_add_kernel(
    const float* __restrict__ xin, float* __restrict__ xout)
{
    const int t = blockIdx.x * blockDim.x + threadIdx.x;  // 0 .. SD/4-1
    const int s = t >> 8;                 // 256 float4 vectors per seq position
    const int dbase = (t & 255) << 2;     // starting dim, multiple of 4 (even)

    const float pos = (float)s;
    float pe[4];
#pragma unroll
    for (int j = 0; j < 4; ++j) {
        const float invfreq = exp2f(C_FREQ * (float)(dbase + j));  // v_exp_f32
        const float rev = pos * invfreq * INV_2PI;                 // angle in revolutions
        const float r = rev - floorf(rev);                         // v_fract range reduce
        pe[j] = (j & 1) ? __builtin_amdgcn_cosf(r)                 // v_cos_f32: cos(2*pi*r)
                        : __builtin_amdgcn_sinf(r);                // v_sin_f32: sin(2*pi*r)
    }
    v4f pv;
    pv.x = pe[0]; pv.y = pe[1]; pv.z = pe[2]; pv.w = pe[3];

    const size_t base = (size_t)t * 4;
#pragma unroll
    for (int b = 0; b < BATCH; ++b) {
        const size_t off = (size_t)b * (size_t)SD + base;
        v4f x = *reinterpret_cast<const v4f*>(xin + off);   // plain dwordx4
        x += pv;
        *reinterpret_cast<v4f*>(xout + off) = x;            // plain dwordx4
    }
}

extern "C" void kernel_launch(void* const* d_in, const int* in_sizes, int n_in,
                              void* d_out, int out_size, void* d_ws, size_t ws_size,
                              hipStream_t stream) {
    const float* x = (const float*)d_in[0];
    float* out = (float*)d_out;
    const int threads = 256;
    const int blocks = (SD / 4) / threads;   // 4096 blocks, exact cover
    pe_add_kernel<<<blocks, threads, 0, stream>>>(x, out);
}